// Round 2
// baseline (600.309 us; speedup 1.0000x reference)
//
#include <hip/hip_runtime.h>
#include <cstdint>
#include <cstddef>

#define S_DIM 1024
#define NPTS (S_DIM * S_DIM)
#define NLEV 16
#define TBL (1u << 19)
#define TMASK (TBL - 1u)
#define PRIME_Y 2654435761u

// Fully fused: hash-grid encode (16 levels) + 3-layer MLP, one thread per point.
// fp32 throughout (no fp32 MFMA on CDNA4; threshold needs fp32-grade accuracy).
//
// __launch_bounds__(256, 2): min 2 waves/EU -> VGPR budget 256/wave. Round 1
// showed the default cap (80 VGPR) spilled h0[64]+enc[32] to scratch:
// WRITE_SIZE was 274 MB vs 12.6 MB ideal. The live set here is ~130 floats;
// at ~170 VGPR we get 3 waves/EU, zero spill.
__global__ __launch_bounds__(256, 2) void ngp_fused(
    const float* __restrict__ xy,
    const float* __restrict__ tables,
    const float* __restrict__ W0,
    const float* __restrict__ W1,
    const float* __restrict__ W2,
    float* __restrict__ out)
{
    const int gid = blockIdx.x * 256 + threadIdx.x;

    const float2 p = ((const float2*)xy)[gid];
    const float x = p.x, y = p.y;

    // resolutions: floor(16 * 1.5^l)
    constexpr int RES[NLEV] = {16, 24, 36, 54, 81, 121, 182, 273,
                               410, 615, 922, 1383, 2075, 3113, 4670, 7006};

    float enc[32];

    #pragma unroll
    for (int l = 0; l < NLEV; ++l) {
        const int res = RES[l];
        const float fr = (float)res;
        const float px = x * fr;
        const float py = y * fr;
        const float fx = floorf(px), fy = floorf(py);
        const float wx = px - fx, wy = py - fy;
        const int x0 = (int)fx, y0 = (int)fy;

        int i00, i01, i10, i11;
        // dense iff (res+1)^2 <= T  -> levels 0..9
        const bool dense = ((long long)(res + 1) * (long long)(res + 1) <= (long long)TBL);
        if (dense) {
            const int st = res + 1;
            i00 = x0 + y0 * st;
            i01 = x0 + (y0 + 1) * st;
            i10 = i00 + 1;
            i11 = i01 + 1;
        } else {
            const unsigned a = (unsigned)x0, b = (unsigned)y0;
            const unsigned hb0 = b * PRIME_Y;
            const unsigned hb1 = (b + 1u) * PRIME_Y;
            i00 = (int)((a ^ hb0) & TMASK);
            i01 = (int)((a ^ hb1) & TMASK);
            i10 = (int)(((a + 1u) ^ hb0) & TMASK);
            i11 = (int)(((a + 1u) ^ hb1) & TMASK);
        }

        const float* tb = tables + (size_t)l * (size_t)(TBL * 2u);
        const float2 f00 = *(const float2*)(tb + 2 * (size_t)i00);
        const float2 f01 = *(const float2*)(tb + 2 * (size_t)i01);
        const float2 f10 = *(const float2*)(tb + 2 * (size_t)i10);
        const float2 f11 = *(const float2*)(tb + 2 * (size_t)i11);

        const float omx = 1.f - wx, omy = 1.f - wy;
        const float w00 = omx * omy, w01 = omx * wy, w10 = wx * omy, w11 = wx * wy;

        enc[2 * l]     = f00.x * w00 + f01.x * w01 + f10.x * w10 + f11.x * w11;
        enc[2 * l + 1] = f00.y * w00 + f01.y * w01 + f10.y * w10 + f11.y * w11;
    }

    // ---- Layer 0: h0 = relu(enc @ W0), W0 is (32,64) row-major ----
    float h0[64];
    #pragma unroll 4
    for (int j = 0; j < 64; j += 4) {
        float a0 = 0.f, a1 = 0.f, a2 = 0.f, a3 = 0.f;
        #pragma unroll
        for (int k = 0; k < 32; ++k) {
            const float e = enc[k];
            const float* w = W0 + k * 64 + j;   // uniform address -> s_load
            a0 = fmaf(e, w[0], a0);
            a1 = fmaf(e, w[1], a1);
            a2 = fmaf(e, w[2], a2);
            a3 = fmaf(e, w[3], a3);
        }
        h0[j + 0] = fmaxf(a0, 0.f);
        h0[j + 1] = fmaxf(a1, 0.f);
        h0[j + 2] = fmaxf(a2, 0.f);
        h0[j + 3] = fmaxf(a3, 0.f);
    }

    // ---- Layer 1 + Layer 2 fused: out += relu(h0 @ W1)[j] * W2[j,:] ----
    float o0 = 0.f, o1 = 0.f, o2 = 0.f;
    #pragma unroll 2
    for (int j = 0; j < 64; j += 4) {
        float a0 = 0.f, a1 = 0.f, a2 = 0.f, a3 = 0.f;
        #pragma unroll
        for (int k = 0; k < 64; ++k) {
            const float h = h0[k];
            const float* w = W1 + k * 64 + j;   // uniform address -> s_load
            a0 = fmaf(h, w[0], a0);
            a1 = fmaf(h, w[1], a1);
            a2 = fmaf(h, w[2], a2);
            a3 = fmaf(h, w[3], a3);
        }
        a0 = fmaxf(a0, 0.f);
        a1 = fmaxf(a1, 0.f);
        a2 = fmaxf(a2, 0.f);
        a3 = fmaxf(a3, 0.f);

        const float* w2a = W2 + (j + 0) * 3;
        const float* w2b = W2 + (j + 1) * 3;
        const float* w2c = W2 + (j + 2) * 3;
        const float* w2d = W2 + (j + 3) * 3;
        o0 = fmaf(a0, w2a[0], o0); o1 = fmaf(a0, w2a[1], o1); o2 = fmaf(a0, w2a[2], o2);
        o0 = fmaf(a1, w2b[0], o0); o1 = fmaf(a1, w2b[1], o1); o2 = fmaf(a1, w2b[2], o2);
        o0 = fmaf(a2, w2c[0], o0); o1 = fmaf(a2, w2c[1], o1); o2 = fmaf(a2, w2c[2], o2);
        o0 = fmaf(a3, w2d[0], o0); o1 = fmaf(a3, w2d[1], o1); o2 = fmaf(a3, w2d[2], o2);
    }

    // output layout: (3, S, S) with point index = row-major over (S,S)
    out[0 * NPTS + gid] = o0;
    out[1 * NPTS + gid] = o1;
    out[2 * NPTS + gid] = o2;
}

extern "C" void kernel_launch(void* const* d_in, const int* in_sizes, int n_in,
                              void* d_out, int out_size, void* d_ws, size_t ws_size,
                              hipStream_t stream) {
    const float* xy     = (const float*)d_in[0];
    const float* tables = (const float*)d_in[1];
    const float* W0     = (const float*)d_in[2];
    const float* W1     = (const float*)d_in[3];
    const float* W2     = (const float*)d_in[4];
    float* out = (float*)d_out;

    dim3 grid(NPTS / 256);
    dim3 block(256);
    hipLaunchKernelGGL(ngp_fused, grid, block, 0, stream, xy, tables, W0, W1, W2, out);
}

// Round 3
// 298.273 us; speedup vs baseline: 2.0126x; 2.0126x over previous
//
#include <hip/hip_runtime.h>
#include <cstdint>
#include <cstddef>

#define S_DIM 1024
#define NPTS (S_DIM * S_DIM)
#define NLEV 16
#define TBL (1u << 19)
#define TMASK (TBL - 1u)
#define PRIME_Y 2654435761u

// Fully fused: hash-grid encode (16 levels) + 3-layer MLP, one thread per point.
//
// KEY STRUCTURAL RULE (round-2 lesson): every per-thread array index must be a
// compile-time constant, or LLVM demotes the array to scratch (round 1/2:
// 256 MB of scratch spill from h0[j] with partially-unrolled j). Here the only
// rolled loop variable is j (layer-0 neuron), which only ever indexes WEIGHTS
// (wave-uniform addresses -> s_load); enc[] and h1[] are always const-indexed.
__global__ __launch_bounds__(256, 2) void ngp_fused(
    const float* __restrict__ xy,
    const float* __restrict__ tables,
    const float* __restrict__ W0,
    const float* __restrict__ W1,
    const float* __restrict__ W2,
    float* __restrict__ out)
{
    const int gid = blockIdx.x * 256 + threadIdx.x;

    const float2 p = ((const float2*)xy)[gid];
    const float x = p.x, y = p.y;

    // resolutions: floor(16 * 1.5^l)
    constexpr int RES[NLEV] = {16, 24, 36, 54, 81, 121, 182, 273,
                               410, 615, 922, 1383, 2075, 3113, 4670, 7006};

    float enc[32];

    #pragma unroll
    for (int l = 0; l < NLEV; ++l) {
        const int res = RES[l];
        const float fr = (float)res;
        const float px = x * fr;
        const float py = y * fr;
        const float fx = floorf(px), fy = floorf(py);
        const float wx = px - fx, wy = py - fy;
        const int x0 = (int)fx, y0 = (int)fy;

        int i00, i01, i10, i11;
        // dense iff (res+1)^2 <= T  -> levels 0..9 (compile-time per level)
        const bool dense = ((long long)(res + 1) * (long long)(res + 1) <= (long long)TBL);
        if (dense) {
            const int st = res + 1;
            i00 = x0 + y0 * st;
            i01 = x0 + (y0 + 1) * st;
            i10 = i00 + 1;
            i11 = i01 + 1;
        } else {
            const unsigned a = (unsigned)x0, b = (unsigned)y0;
            const unsigned hb0 = b * PRIME_Y;
            const unsigned hb1 = (b + 1u) * PRIME_Y;
            i00 = (int)((a ^ hb0) & TMASK);
            i01 = (int)((a ^ hb1) & TMASK);
            i10 = (int)(((a + 1u) ^ hb0) & TMASK);
            i11 = (int)(((a + 1u) ^ hb1) & TMASK);
        }

        const float* tb = tables + (size_t)l * (size_t)(TBL * 2u);
        const float2 f00 = *(const float2*)(tb + 2 * (size_t)i00);
        const float2 f01 = *(const float2*)(tb + 2 * (size_t)i01);
        const float2 f10 = *(const float2*)(tb + 2 * (size_t)i10);
        const float2 f11 = *(const float2*)(tb + 2 * (size_t)i11);

        const float omx = 1.f - wx, omy = 1.f - wy;
        const float w00 = omx * omy, w01 = omx * wy, w10 = wx * omy, w11 = wx * wy;

        enc[2 * l]     = f00.x * w00 + f01.x * w01 + f10.x * w10 + f11.x * w11;
        enc[2 * l + 1] = f00.y * w00 + f01.y * w01 + f10.y * w10 + f11.y * w11;
    }

    // ---- Layers 0+1 fused, j rolled over layer-0 neurons ----
    // h1[k] accumulates pre-activations of layer 1; h0_j never materializes
    // as an array. All enc[]/h1[] indices are compile-time constants.
    float h1[64];
    #pragma unroll
    for (int k = 0; k < 64; ++k) h1[k] = 0.f;

    #pragma unroll 4
    for (int j = 0; j < 64; ++j) {
        // h0_j = dot(enc, W0[:,j]); 4-way split for FMA-latency ILP
        float a0 = 0.f, a1 = 0.f, a2 = 0.f, a3 = 0.f;
        #pragma unroll
        for (int k = 0; k < 32; k += 4) {
            a0 = fmaf(enc[k + 0], W0[(k + 0) * 64 + j], a0);
            a1 = fmaf(enc[k + 1], W0[(k + 1) * 64 + j], a1);
            a2 = fmaf(enc[k + 2], W0[(k + 2) * 64 + j], a2);
            a3 = fmaf(enc[k + 3], W0[(k + 3) * 64 + j], a3);
        }
        const float a = fmaxf((a0 + a1) + (a2 + a3), 0.f);

        const float* w1r = W1 + j * 64;   // contiguous row, uniform -> s_load
        #pragma unroll
        for (int k = 0; k < 64; ++k) {
            h1[k] = fmaf(a, w1r[k], h1[k]);
        }
    }

    // ---- Layer 2: out = relu(h1) @ W2, W2 is (64,3) row-major ----
    float o0 = 0.f, o1 = 0.f, o2 = 0.f;
    #pragma unroll
    for (int k = 0; k < 64; ++k) {
        const float h = fmaxf(h1[k], 0.f);
        o0 = fmaf(h, W2[k * 3 + 0], o0);
        o1 = fmaf(h, W2[k * 3 + 1], o1);
        o2 = fmaf(h, W2[k * 3 + 2], o2);
    }

    // output layout: (3, S, S) with point index = row-major over (S,S)
    out[0 * NPTS + gid] = o0;
    out[1 * NPTS + gid] = o1;
    out[2 * NPTS + gid] = o2;
}

extern "C" void kernel_launch(void* const* d_in, const int* in_sizes, int n_in,
                              void* d_out, int out_size, void* d_ws, size_t ws_size,
                              hipStream_t stream) {
    const float* xy     = (const float*)d_in[0];
    const float* tables = (const float*)d_in[1];
    const float* W0     = (const float*)d_in[2];
    const float* W1     = (const float*)d_in[3];
    const float* W2     = (const float*)d_in[4];
    float* out = (float*)d_out;

    dim3 grid(NPTS / 256);
    dim3 block(256);
    hipLaunchKernelGGL(ngp_fused, grid, block, 0, stream, xy, tables, W0, W1, W2, out);
}